// Round 1
// baseline (209.841 us; speedup 1.0000x reference)
//
#include <hip/hip_runtime.h>
#include <hip/hip_bf16.h>
#include <stdint.h>

#define H 16
#define D 128
#define BM 128      // q rows per block
#define BN 64       // kv rows per tile
#define NTHREADS 512

typedef __bf16 bf16_t;
typedef bf16_t bf16x8 __attribute__((ext_vector_type(8)));
typedef bf16_t bf16x2 __attribute__((ext_vector_type(2)));
typedef float f32x4 __attribute__((ext_vector_type(4)));

#define MFMA(a, b, c) __builtin_amdgcn_mfma_f32_16x16x32_bf16(a, b, c, 0, 0, 0)

__global__ __launch_bounds__(NTHREADS, 1)
void fa_varlen(const float* __restrict__ q,
               const float* __restrict__ k,
               const float* __restrict__ v,
               const int* __restrict__ cuq,
               const int* __restrict__ cuk,
               float* __restrict__ out,
               int nseq)
{
  __shared__ alignas(16) bf16_t sK[BN * D];    // row-major, swizzled (16 chunks/row)
  __shared__ alignas(16) bf16_t sVt[D * BN];   // transposed [d][kv], swizzled (8 chunks/row)
  __shared__ alignas(16) bf16_t sP[BM * BN];   // [q][kv], swizzled (8 chunks/row)

  const int tile = blockIdx.x;
  const int h = blockIdx.y;

  // ---- map flat tile index -> (seq, local tile) via cu_seqlens scan ----
  int acc = 0, seq = -1, lt = 0, s0q = 0, s0k = 0, Lq = 0, Lk = 0;
  for (int s = 0; s < nseq; ++s) {
    int a = cuq[s], b = cuq[s + 1];
    int Ls = b - a;
    int nt = (Ls + BM - 1) / BM;
    if (tile < acc + nt) {
      seq = s; lt = tile - acc; s0q = a; Lq = Ls;
      s0k = cuk[s]; Lk = cuk[s + 1] - s0k;
      break;
    }
    acc += nt;
  }
  if (seq < 0) return;

  const int q0 = lt * BM;
  const int tid = threadIdx.x;
  const int wave = tid >> 6;
  const int lane = tid & 63;
  const int lr = lane & 15;   // frag "row" lane index / C col
  const int lg = lane >> 4;   // lane group 0..3

  // scale * log2(e): softmax done in exp2 domain
  const float SC = 0.08838834764831845f * 1.44269504088896340f;

  // ---- Q fragments (loop-invariant): lane holds Q[q0+wave*16+lr][ks*32+lg*8+i] ----
  bf16x8 qf[4];
  {
    int qr = q0 + wave * 16 + lr;
    if (qr >= Lq) qr = Lq - 1;                 // clamp; garbage rows never stored
    const float* qp = q + ((size_t)(s0q + qr) * H + h) * D;
    #pragma unroll
    for (int ks = 0; ks < 4; ++ks) {
      const float* p = qp + ks * 32 + lg * 8;
      bf16x8 r;
      #pragma unroll
      for (int i = 0; i < 8; ++i) r[i] = (bf16_t)p[i];
      qf[ks] = r;
    }
  }

  f32x4 oacc[8];
  #pragma unroll
  for (int i = 0; i < 8; ++i) oacc[i] = (f32x4){0.f, 0.f, 0.f, 0.f};
  float mrow[4], lrow[4];
  #pragma unroll
  for (int i = 0; i < 4; ++i) { mrow[i] = -1e30f; lrow[i] = 0.f; }

  const int nkv = (Lk + BN - 1) / BN;
  for (int it = 0; it < nkv; ++it) {
    const int kv0 = it * BN;

    __syncthreads();  // previous tile's LDS reads complete

    // ---- stage K tile: 64x128 f32 -> bf16 LDS (swizzled), coalesced ----
    #pragma unroll
    for (int ii = 0; ii < 2; ++ii) {
      int g = tid + ii * NTHREADS;        // 0..1023 chunks
      int row = g >> 4, cc = g & 15;
      int gr = kv0 + row; if (gr >= Lk) gr = Lk - 1;
      const float* p = k + ((size_t)(s0k + gr) * H + h) * D + cc * 8;
      float4 f0 = *(const float4*)p;
      float4 f1 = *(const float4*)(p + 4);
      bf16x8 w;
      w[0] = (bf16_t)f0.x; w[1] = (bf16_t)f0.y; w[2] = (bf16_t)f0.z; w[3] = (bf16_t)f0.w;
      w[4] = (bf16_t)f1.x; w[5] = (bf16_t)f1.y; w[6] = (bf16_t)f1.z; w[7] = (bf16_t)f1.w;
      *(bf16x8*)&sK[row * D + ((cc ^ (row & 7)) << 3)] = w;
    }

    // ---- stage V transposed: sVt[d][kv], kv-pair packed b32 writes (bank-clean) ----
    {
      int kp = tid & 31;                  // kv rows 2kp, 2kp+1
      int seg = tid >> 5;                 // d range seg*8 .. +7
      int r0 = kv0 + 2 * kp, r1 = r0 + 1;
      if (r0 >= Lk) r0 = Lk - 1;
      if (r1 >= Lk) r1 = Lk - 1;
      const float* p0 = v + ((size_t)(s0k + r0) * H + h) * D + seg * 8;
      const float* p1 = v + ((size_t)(s0k + r1) * H + h) * D + seg * 8;
      float va[8], vb[8];
      *(float4*)&va[0] = *(const float4*)p0;
      *(float4*)&va[4] = *(const float4*)(p0 + 4);
      *(float4*)&vb[0] = *(const float4*)p1;
      *(float4*)&vb[4] = *(const float4*)(p1 + 4);
      int kvr = 2 * kp;
      #pragma unroll
      for (int i = 0; i < 8; ++i) {
        int d = seg * 8 + i;
        int ck = (kvr >> 3) ^ (d & 7);
        bf16x2 w2; w2[0] = (bf16_t)va[i]; w2[1] = (bf16_t)vb[i];
        *(bf16x2*)&sVt[d * BN + (ck << 3) + (kvr & 7)] = w2;
      }
    }

    __syncthreads();  // staged data visible

    // ---- S = Q K^T : wave's 16 q-rows x 64 kv-cols, 16 MFMAs ----
    f32x4 sacc[4];
    #pragma unroll
    for (int ct = 0; ct < 4; ++ct) {
      sacc[ct] = (f32x4){0.f, 0.f, 0.f, 0.f};
      int krow = ct * 16 + lr;
      #pragma unroll
      for (int ks = 0; ks < 4; ++ks) {
        bf16x8 bf = *(const bf16x8*)&sK[krow * D + (((ks * 4 + lg) ^ (krow & 7)) << 3)];
        sacc[ct] = MFMA(qf[ks], bf, sacc[ct]);
      }
    }

    // ---- online softmax (C layout: col=lane&15, row=lg*4+reg) ----
    float tmax[4];
    #pragma unroll
    for (int r = 0; r < 4; ++r) tmax[r] = -1e30f;
    #pragma unroll
    for (int ct = 0; ct < 4; ++ct) {
      bool valid = (kv0 + ct * 16 + lr) < Lk;
      #pragma unroll
      for (int r = 0; r < 4; ++r) {
        float t = valid ? sacc[ct][r] * SC : -1e30f;
        sacc[ct][r] = t;
        tmax[r] = fmaxf(tmax[r], t);
      }
    }
    #pragma unroll
    for (int m = 1; m < 16; m <<= 1) {
      #pragma unroll
      for (int r = 0; r < 4; ++r)
        tmax[r] = fmaxf(tmax[r], __shfl_xor(tmax[r], m, 64));
    }

    float alpha[4], psum[4];
    #pragma unroll
    for (int r = 0; r < 4; ++r) {
      float mn = fmaxf(mrow[r], tmax[r]);
      alpha[r] = exp2f(mrow[r] - mn);
      mrow[r] = mn;
      psum[r] = 0.f;
    }

    // p = exp2(t - m) -> bf16 -> sP (swizzled scatter, wave-private rows)
    #pragma unroll
    for (int ct = 0; ct < 4; ++ct) {
      int kvc = ct * 16 + lr;
      #pragma unroll
      for (int r = 0; r < 4; ++r) {
        int qr = wave * 16 + lg * 4 + r;
        float p = exp2f(sacc[ct][r] - mrow[r]);
        psum[r] += p;
        sP[qr * BN + ((((kvc >> 3) ^ (qr & 7))) << 3) + (kvc & 7)] = (bf16_t)p;
      }
    }
    #pragma unroll
    for (int m = 1; m < 16; m <<= 1) {
      #pragma unroll
      for (int r = 0; r < 4; ++r)
        psum[r] += __shfl_xor(psum[r], m, 64);
    }
    #pragma unroll
    for (int r = 0; r < 4; ++r)
      lrow[r] = lrow[r] * alpha[r] + psum[r];
    #pragma unroll
    for (int dt = 0; dt < 8; ++dt) {
      #pragma unroll
      for (int r = 0; r < 4; ++r)
        oacc[dt][r] *= alpha[r];
    }

    __syncthreads();  // sP visible (cross-lane within wave; barrier keeps it simple)

    // ---- O += P V : 16 MFMAs ----
    int prow = wave * 16 + lr;
    #pragma unroll
    for (int ks = 0; ks < 2; ++ks) {
      bf16x8 pf = *(const bf16x8*)&sP[prow * BN + (((ks * 4 + lg) ^ (prow & 7)) << 3)];
      #pragma unroll
      for (int dt = 0; dt < 8; ++dt) {
        int vrow = dt * 16 + lr;
        bf16x8 vf = *(const bf16x8*)&sVt[vrow * BN + (((ks * 4 + lg) ^ (vrow & 7)) << 3)];
        oacc[dt] = MFMA(pf, vf, oacc[dt]);
      }
    }
  }

  // ---- epilogue: normalize and store ----
  float rcp[4];
  #pragma unroll
  for (int r = 0; r < 4; ++r) rcp[r] = 1.f / lrow[r];
  #pragma unroll
  for (int r = 0; r < 4; ++r) {
    int qr = q0 + wave * 16 + lg * 4 + r;
    if (qr < Lq) {
      float* op = out + ((size_t)(s0q + qr) * H + h) * D;
      #pragma unroll
      for (int dt = 0; dt < 8; ++dt)
        op[dt * 16 + lr] = oacc[dt][r] * rcp[r];
    }
  }
}

extern "C" void kernel_launch(void* const* d_in, const int* in_sizes, int n_in,
                              void* d_out, int out_size, void* d_ws, size_t ws_size,
                              hipStream_t stream) {
  const float* q = (const float*)d_in[0];
  const float* k = (const float*)d_in[1];
  const float* v = (const float*)d_in[2];
  const int* cuq = (const int*)d_in[3];
  const int* cuk = (const int*)d_in[4];
  float* out = (float*)d_out;

  int total = in_sizes[0] / (H * D);
  int nseq = in_sizes[3] - 1;
  int maxtiles = (total + BM - 1) / BM + nseq;  // upper bound on sum ceil(L_i/BM)

  dim3 grid(maxtiles, H);
  fa_varlen<<<grid, NTHREADS, 0, stream>>>(q, k, v, cuq, cuk, out, nseq);
}

// Round 2
// 188.773 us; speedup vs baseline: 1.1116x; 1.1116x over previous
//
#include <hip/hip_runtime.h>
#include <hip/hip_bf16.h>
#include <stdint.h>

#define H 16
#define D 128
#define BM 128      // q rows per block (4 warps x 32)
#define BN 64       // kv rows per tile
#define NW 4
#define NT 256

typedef __bf16 bf16_t;
typedef bf16_t bf16x8 __attribute__((ext_vector_type(8)));
typedef bf16_t bf16x2 __attribute__((ext_vector_type(2)));
typedef float f32x16 __attribute__((ext_vector_type(16)));

#define MFMA32(a, b, c) __builtin_amdgcn_mfma_f32_32x32x16_bf16(a, b, c, 0, 0, 0)

union FragU { uint32_t w[4]; bf16x8 v; };

static __device__ __forceinline__ uint32_t cvtpk_bf16(float lo, float hi) {
  uint32_t r;
  asm("v_cvt_pk_bf16_f32 %0, %1, %2" : "=v"(r) : "v"(lo), "v"(hi));
  return r;
}

__global__ __launch_bounds__(NT, 3)
void fa_varlen2(const float* __restrict__ q,
                const float* __restrict__ k,
                const float* __restrict__ v,
                const int* __restrict__ cuq,
                const int* __restrict__ cuk,
                float* __restrict__ out,
                int nseq)
{
  // sBuf: Q staging (128x128 bf16 = 32KB) in prologue; K (64x128) + Vt (128x64) in main loop
  __shared__ alignas(16) bf16_t sBuf[128 * 128];
  __shared__ float sRed[NW * 32];
  bf16_t* sK  = sBuf;
  bf16_t* sVt = sBuf + 64 * 128;

  const int tile = blockIdx.x;
  const int h = blockIdx.y;

  // ---- map flat tile -> (seq, local tile) ----
  int acc = 0, seq = -1, lt = 0, s0q = 0, s0k = 0, Lq = 0, Lk = 0;
  for (int s = 0; s < nseq; ++s) {
    int a = cuq[s], b = cuq[s + 1];
    int Ls = b - a;
    int nt = (Ls + BM - 1) / BM;
    if (tile < acc + nt) {
      seq = s; lt = tile - acc; s0q = a; Lq = Ls;
      s0k = cuk[s]; Lk = cuk[s + 1] - s0k;
      break;
    }
    acc += nt;
  }
  if (seq < 0) return;

  const int q0 = lt * BM;
  const int tid = threadIdx.x;
  const int warp = tid >> 6;
  const int lane = tid & 63;
  const int lq = lane & 31;     // q col for St / d col for O
  const int hi = lane >> 5;

  const float SC = 0.08838834764831845f * 1.44269504088896340f; // 1/sqrt(128) * log2(e)

  // ---- stage Q tile as bf16 (swizzled), 128 rows x 16 chunks ----
  #pragma unroll
  for (int ii = 0; ii < 8; ++ii) {
    int g = tid + ii * NT;             // 0..2047
    int row = g >> 4, cc = g & 15;
    int gr = q0 + row; if (gr >= Lq) gr = Lq - 1;
    const float* p = q + ((size_t)(s0q + gr) * H + h) * D + cc * 8;
    float4 f0 = *(const float4*)p;
    float4 f1 = *(const float4*)(p + 4);
    bf16x8 w;
    w[0] = (bf16_t)f0.x; w[1] = (bf16_t)f0.y; w[2] = (bf16_t)f0.z; w[3] = (bf16_t)f0.w;
    w[4] = (bf16_t)f1.x; w[5] = (bf16_t)f1.y; w[6] = (bf16_t)f1.z; w[7] = (bf16_t)f1.w;
    *(bf16x8*)&sBuf[row * 128 + (((cc ^ (row & 7))) << 3)] = w;
  }
  __syncthreads();

  // ---- Q fragments in registers: qf[ks], lane holds Q[q=warp*32+lq][d=ks*16+hi*8+i] ----
  bf16x8 qf[8];
  {
    int row = warp * 32 + lq;
    #pragma unroll
    for (int ks = 0; ks < 8; ++ks) {
      int pos = (ks * 2 + hi) ^ (row & 7);
      qf[ks] = *(const bf16x8*)&sBuf[row * 128 + (pos << 3)];
    }
  }

  f32x16 oacc[4];
  #pragma unroll
  for (int dt = 0; dt < 4; ++dt)
    #pragma unroll
    for (int r = 0; r < 16; ++r) oacc[dt][r] = 0.f;
  float m = -1e30f, l = 0.f;

  const int nkv = (Lk + BN - 1) / BN;
  for (int it = 0; it < nkv; ++it) {
    const int kv0 = it * BN;
    __syncthreads();   // prior LDS reads (qf load / previous tile) complete

    // ---- stage K: 64 rows x 16 chunks, swizzled bf16 ----
    #pragma unroll
    for (int ii = 0; ii < 4; ++ii) {
      int g = tid + ii * NT;           // 0..1023
      int row = g >> 4, cc = g & 15;
      int gr = kv0 + row; if (gr >= Lk) gr = Lk - 1;
      const float* p = k + ((size_t)(s0k + gr) * H + h) * D + cc * 8;
      float4 f0 = *(const float4*)p;
      float4 f1 = *(const float4*)(p + 4);
      bf16x8 w;
      w[0] = (bf16_t)f0.x; w[1] = (bf16_t)f0.y; w[2] = (bf16_t)f0.z; w[3] = (bf16_t)f0.w;
      w[4] = (bf16_t)f1.x; w[5] = (bf16_t)f1.y; w[6] = (bf16_t)f1.z; w[7] = (bf16_t)f1.w;
      *(bf16x8*)&sK[row * 128 + (((cc ^ (row & 7))) << 3)] = w;
    }

    // ---- stage V transposed: sVt[d][kv], kv-pair b32 writes, swizzled ----
    {
      int kp = tid & 31;               // kv pair index -> rows 2kp, 2kp+1
      int seg = tid >> 5;              // d segment: seg*16 .. +15
      int r0 = kv0 + 2 * kp, r1 = r0 + 1;
      if (r0 >= Lk) r0 = Lk - 1;
      if (r1 >= Lk) r1 = Lk - 1;
      const float* p0 = v + ((size_t)(s0k + r0) * H + h) * D + seg * 16;
      const float* p1 = v + ((size_t)(s0k + r1) * H + h) * D + seg * 16;
      float va[16], vb[16];
      *(float4*)&va[0]  = *(const float4*)p0;
      *(float4*)&va[4]  = *(const float4*)(p0 + 4);
      *(float4*)&va[8]  = *(const float4*)(p0 + 8);
      *(float4*)&va[12] = *(const float4*)(p0 + 12);
      *(float4*)&vb[0]  = *(const float4*)p1;
      *(float4*)&vb[4]  = *(const float4*)(p1 + 4);
      *(float4*)&vb[8]  = *(const float4*)(p1 + 8);
      *(float4*)&vb[12] = *(const float4*)(p1 + 12);
      int kvr = 2 * kp;
      #pragma unroll
      for (int i = 0; i < 16; ++i) {
        int d = seg * 16 + i;
        int pos = (kp >> 2) ^ (d & 7);
        bf16x2 w2; w2[0] = (bf16_t)va[i]; w2[1] = (bf16_t)vb[i];
        *(bf16x2*)&sVt[d * 64 + (pos << 3) + (kvr & 7)] = w2;
      }
    }
    __syncthreads();

    const bool tail = (kv0 + BN > Lk);

    #pragma unroll
    for (int ct = 0; ct < 2; ++ct) {
      // ---- QK^T swapped: St[kv][q], lane holds q=lq, kv=ct*32+crow(r,hi) ----
      f32x16 st;
      #pragma unroll
      for (int r = 0; r < 16; ++r) st[r] = 0.f;
      int krow = ct * 32 + lq;
      #pragma unroll
      for (int ks = 0; ks < 8; ++ks) {
        int pos = (ks * 2 + hi) ^ (krow & 7);
        bf16x8 kf = *(const bf16x8*)&sK[krow * 128 + (pos << 3)];
        st = MFMA32(kf, qf[ks], st);
      }

      // ---- online softmax, exp2 domain, defer-max THR=8 ----
      float tmax = -1e30f;
      #pragma unroll
      for (int r = 0; r < 16; ++r) {
        float x = st[r] * SC;
        if (tail) {
          int kvi = kv0 + ct * 32 + (r & 3) + 8 * (r >> 2) + 4 * hi;
          if (kvi >= Lk) x = -1e30f;
        }
        st[r] = x;
        tmax = fmaxf(tmax, x);
      }
      tmax = fmaxf(tmax, __shfl_xor(tmax, 32));
      bool trig = tmax > m + 8.0f;
      float mnew = trig ? tmax : m;
      float alpha = exp2f(m - mnew);   // == 1.0 when not triggered
      m = mnew;

      float psum = 0.f;
      #pragma unroll
      for (int r = 0; r < 16; ++r) {
        float e = exp2f(st[r] - m);
        st[r] = e;
        psum += e;
      }
      psum += __shfl_xor(psum, 32);
      l = l * alpha + psum;

      if (__any(alpha != 1.0f)) {
        // broadcast per-q alpha to the crow-indexed O lanes via per-warp LDS row
        if (hi == 0) sRed[warp * 32 + lq] = alpha;
        #pragma unroll
        for (int r = 0; r < 16; ++r) {
          float a2 = sRed[warp * 32 + (r & 3) + 8 * (r >> 2) + 4 * hi];
          #pragma unroll
          for (int dt = 0; dt < 4; ++dt) oacc[dt][r] *= a2;
        }
      }

      // ---- pack P -> bf16 A-frags via cvt_pk + permlane32_swap (T12) ----
      uint32_t c0 = cvtpk_bf16(st[0],  st[1]),  c1 = cvtpk_bf16(st[2],  st[3]);
      uint32_t c2 = cvtpk_bf16(st[4],  st[5]),  c3 = cvtpk_bf16(st[6],  st[7]);
      uint32_t c4 = cvtpk_bf16(st[8],  st[9]),  c5 = cvtpk_bf16(st[10], st[11]);
      uint32_t c6 = cvtpk_bf16(st[12], st[13]), c7 = cvtpk_bf16(st[14], st[15]);
      { auto rr = __builtin_amdgcn_permlane32_swap(c0, c2, false, false); c0 = rr[0]; c2 = rr[1]; }
      { auto rr = __builtin_amdgcn_permlane32_swap(c1, c3, false, false); c1 = rr[0]; c3 = rr[1]; }
      { auto rr = __builtin_amdgcn_permlane32_swap(c4, c6, false, false); c4 = rr[0]; c6 = rr[1]; }
      { auto rr = __builtin_amdgcn_permlane32_swap(c5, c7, false, false); c5 = rr[0]; c7 = rr[1]; }
      FragU pa, pb;
      pa.w[0] = c0; pa.w[1] = c1; pa.w[2] = c2; pa.w[3] = c3;  // kv ks2=0 (0..15)
      pb.w[0] = c4; pb.w[1] = c5; pb.w[2] = c6; pb.w[3] = c7;  // kv ks2=1 (16..31)

      // ---- O += P V : O[q=crow][d=lq], 8 MFMAs per ct ----
      #pragma unroll
      for (int dt = 0; dt < 4; ++dt) {
        int drow = dt * 32 + lq;
        int pos0 = (ct * 4 + hi) ^ (drow & 7);
        bf16x8 vf0 = *(const bf16x8*)&sVt[drow * 64 + (pos0 << 3)];
        oacc[dt] = MFMA32(pa.v, vf0, oacc[dt]);
        int pos1 = (ct * 4 + 2 + hi) ^ (drow & 7);
        bf16x8 vf1 = *(const bf16x8*)&sVt[drow * 64 + (pos1 << 3)];
        oacc[dt] = MFMA32(pb.v, vf1, oacc[dt]);
      }
    }
  }

  // ---- epilogue: broadcast l to crow lanes, normalize, coalesced store ----
  if (hi == 0) sRed[warp * 32 + lq] = l;
  __builtin_amdgcn_s_waitcnt(0);  // lgkmcnt(0): wave-local LDS visibility
  #pragma unroll
  for (int r = 0; r < 16; ++r) {
    int cr = (r & 3) + 8 * (r >> 2) + 4 * hi;
    int qr = q0 + warp * 32 + cr;
    if (qr < Lq) {
      float rn = 1.0f / sRed[warp * 32 + cr];
      float* op = out + ((size_t)(s0q + qr) * H + h) * D + lq;
      #pragma unroll
      for (int dt = 0; dt < 4; ++dt)
        op[dt * 32] = oacc[dt][r] * rn;
    }
  }
}

extern "C" void kernel_launch(void* const* d_in, const int* in_sizes, int n_in,
                              void* d_out, int out_size, void* d_ws, size_t ws_size,
                              hipStream_t stream) {
  const float* q = (const float*)d_in[0];
  const float* k = (const float*)d_in[1];
  const float* v = (const float*)d_in[2];
  const int* cuq = (const int*)d_in[3];
  const int* cuk = (const int*)d_in[4];
  float* out = (float*)d_out;

  int total = in_sizes[0] / (H * D);
  int nseq = in_sizes[3] - 1;
  int maxtiles = (total + BM - 1) / BM + nseq;  // upper bound on sum ceil(L_i/BM)

  dim3 grid(maxtiles, H);
  fa_varlen2<<<grid, NT, 0, stream>>>(q, k, v, cuq, cuk, out, nseq);
}

// Round 3
// 146.985 us; speedup vs baseline: 1.4276x; 1.2843x over previous
//
#include <hip/hip_runtime.h>
#include <hip/hip_bf16.h>
#include <stdint.h>

#define H 16
#define D 128
#define BM 128      // q rows per block (4 warps x 32)
#define BN 64       // kv rows per tile
#define NW 4
#define NT 256

typedef __bf16 bf16_t;
typedef bf16_t bf16x8 __attribute__((ext_vector_type(8)));
typedef bf16_t bf16x2 __attribute__((ext_vector_type(2)));
typedef float f32x16 __attribute__((ext_vector_type(16)));

#define MFMA32(a, b, c) __builtin_amdgcn_mfma_f32_32x32x16_bf16(a, b, c, 0, 0, 0)

union FragU { uint32_t w[4]; bf16x8 v; };

static __device__ __forceinline__ uint32_t cvtpk_bf16(float lo, float hi) {
  uint32_t r;
  asm("v_cvt_pk_bf16_f32 %0, %1, %2" : "=v"(r) : "v"(lo), "v"(hi));
  return r;
}

static __device__ __forceinline__ void gld_lds16(const bf16_t* g, bf16_t* l) {
  __builtin_amdgcn_global_load_lds(
      (const __attribute__((address_space(1))) void*)g,
      (__attribute__((address_space(3))) void*)l, 16, 0, 0);
}

// ---------------- convert kernels (one-time per launch) ----------------

__global__ void conv_k(const float* __restrict__ kin, bf16_t* __restrict__ kb, int n8) {
  int i = blockIdx.x * blockDim.x + threadIdx.x;
  int stride = gridDim.x * blockDim.x;
  for (; i < n8; i += stride) {
    const float* p = kin + (size_t)i * 8;
    float4 a = *(const float4*)p, b = *(const float4*)(p + 4);
    bf16x8 w;
    w[0] = (bf16_t)a.x; w[1] = (bf16_t)a.y; w[2] = (bf16_t)a.z; w[3] = (bf16_t)a.w;
    w[4] = (bf16_t)b.x; w[5] = (bf16_t)b.y; w[6] = (bf16_t)b.z; w[7] = (bf16_t)b.w;
    *(bf16x8*)(kb + (size_t)i * 8) = w;
  }
}

// V[token][h][d] f32  ->  VT per seq: [h][d][kv] bf16
__global__ void conv_vt(const float* __restrict__ v, bf16_t* __restrict__ vt,
                        const int* __restrict__ cuk, int nseq) {
  int tile = blockIdx.x, h = blockIdx.y;
  int acc = 0, seq = -1, lt = 0, s0k = 0, Lk = 0;
  for (int s = 0; s < nseq; ++s) {
    int a = cuk[s], b = cuk[s + 1];
    int Ls = b - a;
    int nt = (Ls + 63) / 64;
    if (tile < acc + nt) { seq = s; lt = tile - acc; s0k = a; Lk = Ls; break; }
    acc += nt;
  }
  if (seq < 0) return;
  int kv0 = lt * 64;
  int d = threadIdx.x;            // 0..127, coalesced reads
  bf16x8 w[8];
  #pragma unroll
  for (int j = 0; j < 64; ++j) {
    int kv = kv0 + j; if (kv >= Lk) kv = Lk - 1;
    float val = v[((size_t)(s0k + kv) * H + h) * D + d];
    w[j >> 3][j & 7] = (bf16_t)val;
  }
  bf16_t* row = vt + (size_t)s0k * H * D + ((size_t)h * D + d) * Lk + kv0;
  #pragma unroll
  for (int i = 0; i < 8; ++i) *(bf16x8*)(row + i * 8) = w[i];
}

// ---------------- main kernel (bf16 K / VT from workspace) ----------------

__global__ __launch_bounds__(NT, 2)
void fa_varlen3(const float* __restrict__ q,
                const bf16_t* __restrict__ kb,
                const bf16_t* __restrict__ vt,
                const int* __restrict__ cuq,
                const int* __restrict__ cuk,
                float* __restrict__ out,
                int nseq)
{
  __shared__ alignas(16) bf16_t sK[2][BN * D];    // 2 x 16KB, swizzled
  __shared__ alignas(16) bf16_t sVt[2][D * BN];   // 2 x 16KB, swizzled
  __shared__ float sRed[NW * 32];

  const int tile = blockIdx.x;
  const int h = blockIdx.y;

  int acc = 0, seq = -1, lt = 0, s0q = 0, s0k = 0, Lq = 0, Lk = 0;
  for (int s = 0; s < nseq; ++s) {
    int a = cuq[s], b = cuq[s + 1];
    int Ls = b - a;
    int nt = (Ls + BM - 1) / BM;
    if (tile < acc + nt) {
      seq = s; lt = tile - acc; s0q = a; Lq = Ls;
      s0k = cuk[s]; Lk = cuk[s + 1] - s0k;
      break;
    }
    acc += nt;
  }
  if (seq < 0) return;

  const int q0 = lt * BM;
  const int tid = threadIdx.x;
  const int warp = tid >> 6;
  const int lane = tid & 63;
  const int lq = lane & 31;
  const int hi = lane >> 5;

  const float SC = 0.08838834764831845f * 1.44269504088896340f;

  // ---- Q fragments straight from global f32 ----
  bf16x8 qf[8];
  {
    int qrow = q0 + warp * 32 + lq; if (qrow >= Lq) qrow = Lq - 1;
    const float* qp = q + ((size_t)(s0q + qrow) * H + h) * D;
    #pragma unroll
    for (int ks = 0; ks < 8; ++ks) {
      const float* p = qp + ks * 16 + hi * 8;
      float4 a = *(const float4*)p, b = *(const float4*)(p + 4);
      bf16x8 r;
      r[0] = (bf16_t)a.x; r[1] = (bf16_t)a.y; r[2] = (bf16_t)a.z; r[3] = (bf16_t)a.w;
      r[4] = (bf16_t)b.x; r[5] = (bf16_t)b.y; r[6] = (bf16_t)b.z; r[7] = (bf16_t)b.w;
      qf[ks] = r;
    }
  }

  const size_t vtSeqBase = (size_t)s0k * H * D + (size_t)h * D * Lk;

  // stage tile tt into LDS buffer buf: 8 global_load_lds issues, pre-swizzled source
  auto STAGE = [&](int tt, int buf) {
    const int kv0s = tt * BN;
    #pragma unroll
    for (int i = 0; i < 4; ++i) {               // K: rows (warp*4+i)*4 + lane/16
      int blk = warp * 4 + i;
      int row = blk * 4 + (lane >> 4);
      int pos = lane & 15;
      int kvr = kv0s + row; if (kvr >= Lk) kvr = Lk - 1;
      const bf16_t* src = kb + ((size_t)(s0k + kvr) * H + h) * D + ((pos ^ (row & 7)) << 3);
      gld_lds16(src, &sK[buf][blk * 512 + lane * 8]);
    }
    #pragma unroll
    for (int i = 0; i < 4; ++i) {               // VT: d rows (warp*4+i)*8 + lane/8
      int blk = warp * 4 + i;
      int d = blk * 8 + (lane >> 3);
      int posc = lane & 7;
      int ck = posc ^ (d & 7);
      int kvs = kv0s + ck * 8; if (kvs > Lk - 8) kvs = Lk - 8;
      const bf16_t* src = vt + vtSeqBase + (size_t)d * Lk + kvs;
      gld_lds16(src, &sVt[buf][blk * 512 + lane * 8]);
    }
  };

  f32x16 oacc[4];
  #pragma unroll
  for (int dt = 0; dt < 4; ++dt)
    #pragma unroll
    for (int r = 0; r < 16; ++r) oacc[dt][r] = 0.f;
  float m = -1e30f, l = 0.f;

  const int nkv = (Lk + BN - 1) / BN;

  STAGE(0, 0);
  asm volatile("s_waitcnt vmcnt(0)" ::: "memory");
  __syncthreads();

  for (int t = 0; t < nkv; ++t) {
    const int cur = t & 1;
    const int kv0 = t * BN;
    if (t + 1 < nkv) STAGE(t + 1, cur ^ 1);   // prefetch flies under compute

    const bf16_t* sKc = sK[cur];
    const bf16_t* sVc = sVt[cur];
    const bool tail = (kv0 + BN > Lk);

    #pragma unroll
    for (int ct = 0; ct < 2; ++ct) {
      // ---- QK^T swapped: lane holds q=lq, kv=ct*32+crow(r,hi) ----
      f32x16 st;
      #pragma unroll
      for (int r = 0; r < 16; ++r) st[r] = 0.f;
      int krow = ct * 32 + lq;
      __builtin_amdgcn_s_setprio(1);
      #pragma unroll
      for (int ks = 0; ks < 8; ++ks) {
        int pos = (ks * 2 + hi) ^ (krow & 7);
        bf16x8 kf = *(const bf16x8*)&sKc[krow * 128 + (pos << 3)];
        st = MFMA32(kf, qf[ks], st);
      }
      __builtin_amdgcn_s_setprio(0);

      // ---- online softmax, exp2 domain, defer-max THR=8 ----
      float tmax = -1e30f;
      #pragma unroll
      for (int r = 0; r < 16; ++r) {
        float x = st[r] * SC;
        if (tail) {
          int kvi = kv0 + ct * 32 + (r & 3) + 8 * (r >> 2) + 4 * hi;
          if (kvi >= Lk) x = -1e30f;
        }
        st[r] = x;
        tmax = fmaxf(tmax, x);
      }
      tmax = fmaxf(tmax, __shfl_xor(tmax, 32));
      bool trig = tmax > m + 8.0f;
      float mnew = trig ? tmax : m;
      float alpha = exp2f(m - mnew);
      m = mnew;

      float psum = 0.f;
      #pragma unroll
      for (int r = 0; r < 16; ++r) {
        float e = exp2f(st[r] - m);
        st[r] = e;
        psum += e;
      }
      psum += __shfl_xor(psum, 32);
      l = l * alpha + psum;

      if (__any(alpha != 1.0f)) {
        if (hi == 0) sRed[warp * 32 + lq] = alpha;
        asm volatile("s_waitcnt lgkmcnt(0)" ::: "memory");
        #pragma unroll
        for (int r = 0; r < 16; ++r) {
          float a2 = sRed[warp * 32 + (r & 3) + 8 * (r >> 2) + 4 * hi];
          #pragma unroll
          for (int dt = 0; dt < 4; ++dt) oacc[dt][r] *= a2;
        }
      }

      // ---- pack P -> bf16 A-frags (cvt_pk + permlane32_swap) ----
      uint32_t c0 = cvtpk_bf16(st[0],  st[1]),  c1 = cvtpk_bf16(st[2],  st[3]);
      uint32_t c2 = cvtpk_bf16(st[4],  st[5]),  c3 = cvtpk_bf16(st[6],  st[7]);
      uint32_t c4 = cvtpk_bf16(st[8],  st[9]),  c5 = cvtpk_bf16(st[10], st[11]);
      uint32_t c6 = cvtpk_bf16(st[12], st[13]), c7 = cvtpk_bf16(st[14], st[15]);
      { auto rr = __builtin_amdgcn_permlane32_swap(c0, c2, false, false); c0 = rr[0]; c2 = rr[1]; }
      { auto rr = __builtin_amdgcn_permlane32_swap(c1, c3, false, false); c1 = rr[0]; c3 = rr[1]; }
      { auto rr = __builtin_amdgcn_permlane32_swap(c4, c6, false, false); c4 = rr[0]; c6 = rr[1]; }
      { auto rr = __builtin_amdgcn_permlane32_swap(c5, c7, false, false); c5 = rr[0]; c7 = rr[1]; }
      FragU pa, pb;
      pa.w[0] = c0; pa.w[1] = c1; pa.w[2] = c2; pa.w[3] = c3;
      pb.w[0] = c4; pb.w[1] = c5; pb.w[2] = c6; pb.w[3] = c7;

      // ---- O += P V ----
      __builtin_amdgcn_s_setprio(1);
      #pragma unroll
      for (int dt = 0; dt < 4; ++dt) {
        int drow = dt * 32 + lq;
        int pos0 = (ct * 4 + hi) ^ (drow & 7);
        bf16x8 vf0 = *(const bf16x8*)&sVc[drow * 64 + (pos0 << 3)];
        oacc[dt] = MFMA32(pa.v, vf0, oacc[dt]);
        int pos1 = (ct * 4 + 2 + hi) ^ (drow & 7);
        bf16x8 vf1 = *(const bf16x8*)&sVc[drow * 64 + (pos1 << 3)];
        oacc[dt] = MFMA32(pb.v, vf1, oacc[dt]);
      }
      __builtin_amdgcn_s_setprio(0);
    }

    asm volatile("s_waitcnt vmcnt(0)" ::: "memory");  // prefetch landed
    __syncthreads();
  }

  // ---- epilogue ----
  if (hi == 0) sRed[warp * 32 + lq] = l;
  asm volatile("s_waitcnt lgkmcnt(0)" ::: "memory");
  #pragma unroll
  for (int r = 0; r < 16; ++r) {
    int cr = (r & 3) + 8 * (r >> 2) + 4 * hi;
    int qr = q0 + warp * 32 + cr;
    if (qr < Lq) {
      float rn = 1.0f / sRed[warp * 32 + cr];
      float* op = out + ((size_t)(s0q + qr) * H + h) * D + lq;
      #pragma unroll
      for (int dt = 0; dt < 4; ++dt)
        op[dt * 32] = oacc[dt][r] * rn;
    }
  }
}

// ---------------- fallback (round-2 kernel, f32 direct) ----------------

__global__ __launch_bounds__(NT, 3)
void fa_varlen2(const float* __restrict__ q,
                const float* __restrict__ k,
                const float* __restrict__ v,
                const int* __restrict__ cuq,
                const int* __restrict__ cuk,
                float* __restrict__ out,
                int nseq)
{
  __shared__ alignas(16) bf16_t sBuf[128 * 128];
  __shared__ float sRed[NW * 32];
  bf16_t* sK  = sBuf;
  bf16_t* sVt = sBuf + 64 * 128;

  const int tile = blockIdx.x;
  const int h = blockIdx.y;

  int acc = 0, seq = -1, lt = 0, s0q = 0, s0k = 0, Lq = 0, Lk = 0;
  for (int s = 0; s < nseq; ++s) {
    int a = cuq[s], b = cuq[s + 1];
    int Ls = b - a;
    int nt = (Ls + BM - 1) / BM;
    if (tile < acc + nt) {
      seq = s; lt = tile - acc; s0q = a; Lq = Ls;
      s0k = cuk[s]; Lk = cuk[s + 1] - s0k;
      break;
    }
    acc += nt;
  }
  if (seq < 0) return;

  const int q0 = lt * BM;
  const int tid = threadIdx.x;
  const int warp = tid >> 6;
  const int lane = tid & 63;
  const int lq = lane & 31;
  const int hi = lane >> 5;

  const float SC = 0.08838834764831845f * 1.44269504088896340f;

  #pragma unroll
  for (int ii = 0; ii < 8; ++ii) {
    int g = tid + ii * NT;
    int row = g >> 4, cc = g & 15;
    int gr = q0 + row; if (gr >= Lq) gr = Lq - 1;
    const float* p = q + ((size_t)(s0q + gr) * H + h) * D + cc * 8;
    float4 f0 = *(const float4*)p;
    float4 f1 = *(const float4*)(p + 4);
    bf16x8 w;
    w[0] = (bf16_t)f0.x; w[1] = (bf16_t)f0.y; w[2] = (bf16_t)f0.z; w[3] = (bf16_t)f0.w;
    w[4] = (bf16_t)f1.x; w[5] = (bf16_t)f1.y; w[6] = (bf16_t)f1.z; w[7] = (bf16_t)f1.w;
    *(bf16x8*)&sBuf[row * 128 + (((cc ^ (row & 7))) << 3)] = w;
  }
  __syncthreads();

  bf16x8 qf[8];
  {
    int row = warp * 32 + lq;
    #pragma unroll
    for (int ks = 0; ks < 8; ++ks) {
      int pos = (ks * 2 + hi) ^ (row & 7);
      qf[ks] = *(const bf16x8*)&sBuf[row * 128 + (pos << 3)];
    }
  }

  f32x16 oacc[4];
  #pragma unroll
  for (int dt = 0; dt < 4; ++dt)
    #pragma unroll
    for (int r = 0; r < 16; ++r) oacc[dt][r] = 0.f;
  float m = -1e30f, l = 0.f;

  const int nkv = (Lk + BN - 1) / BN;
  for (int it = 0; it < nkv; ++it) {
    const int kv0 = it * BN;
    __syncthreads();

    #pragma unroll
    for (int ii = 0; ii < 4; ++ii) {
      int g = tid + ii * NT;
      int row = g >> 4, cc = g & 15;
      int gr = kv0 + row; if (gr >= Lk) gr = Lk - 1;
      const float* p = k + ((size_t)(s0k + gr) * H + h) * D + cc * 8;
      float4 f0 = *(const float4*)p;
      float4 f1 = *(const float4*)(p + 4);
      bf16x8 w;
      w[0] = (bf16_t)f0.x; w[1] = (bf16_t)f0.y; w[2] = (bf16_t)f0.z; w[3] = (bf16_t)f0.w;
      w[4] = (bf16_t)f1.x; w[5] = (bf16_t)f1.y; w[6] = (bf16_t)f1.z; w[7] = (bf16_t)f1.w;
      *(bf16x8*)&sK[row * 128 + (((cc ^ (row & 7))) << 3)] = w;
    }
    {
      int kp = tid & 31;
      int seg = tid >> 5;
      int r0 = kv0 + 2 * kp, r1 = r0 + 1;
      if (r0 >= Lk) r0 = Lk - 1;
      if (r1 >= Lk) r1 = Lk - 1;
      const float* p0 = v + ((size_t)(s0k + r0) * H + h) * D + seg * 16;
      const float* p1 = v + ((size_t)(s0k + r1) * H + h) * D + seg * 16;
      float va[16], vb[16];
      *(float4*)&va[0]  = *(const float4*)p0;
      *(float4*)&va[4]  = *(const float4*)(p0 + 4);
      *(float4*)&va[8]  = *(const float4*)(p0 + 8);
      *(float4*)&va[12] = *(const float4*)(p0 + 12);
      *(float4*)&vb[0]  = *(const float4*)p1;
      *(float4*)&vb[4]  = *(const float4*)(p1 + 4);
      *(float4*)&vb[8]  = *(const float4*)(p1 + 8);
      *(float4*)&vb[12] = *(const float4*)(p1 + 12);
      int kvr = 2 * kp;
      #pragma unroll
      for (int i = 0; i < 16; ++i) {
        int d = seg * 16 + i;
        int pos = (kp >> 2) ^ (d & 7);
        bf16x2 w2; w2[0] = (bf16_t)va[i]; w2[1] = (bf16_t)vb[i];
        *(bf16x2*)&sVt[d * 64 + (pos << 3) + (kvr & 7)] = w2;
      }
    }
    __syncthreads();

    const bool tail = (kv0 + BN > Lk);

    #pragma unroll
    for (int ct = 0; ct < 2; ++ct) {
      f32x16 st;
      #pragma unroll
      for (int r = 0; r < 16; ++r) st[r] = 0.f;
      int krow = ct * 32 + lq;
      #pragma unroll
      for (int ks = 0; ks < 8; ++ks) {
        int pos = (ks * 2 + hi) ^ (krow & 7);
        bf16x8 kf = *(const bf16x8*)&sK[krow * 128 + (pos << 3)];
        st = MFMA32(kf, qf[ks], st);
      }

      float tmax = -1e30f;
      #pragma unroll
      for (int r = 0; r < 16; ++r) {
        float x = st[r] * SC;
        if (tail) {
          int kvi = kv0 + ct * 32 + (r & 3) + 8 * (r >> 2) + 4 * hi;
          if (kvi >= Lk) x = -1e30f;
        }
        st[r] = x;
        tmax = fmaxf(tmax, x);
      }
      tmax = fmaxf(tmax, __shfl_xor(tmax, 32));
      bool trig = tmax > m + 8.0f;
      float mnew = trig ? tmax : m;
      float alpha = exp2f(m - mnew);
      m = mnew;

      float psum = 0.f;
      #pragma unroll
      for (int r = 0; r < 16; ++r) {
        float e = exp2f(st[r] - m);
        st[r] = e;
        psum += e;
      }
      psum += __shfl_xor(psum, 32);
      l = l * alpha + psum;

      if (__any(alpha != 1.0f)) {
        if (hi == 0) sRed[warp * 32 + lq] = alpha;
        asm volatile("s_waitcnt lgkmcnt(0)" ::: "memory");
        #pragma unroll
        for (int r = 0; r < 16; ++r) {
          float a2 = sRed[warp * 32 + (r & 3) + 8 * (r >> 2) + 4 * hi];
          #pragma unroll
          for (int dt = 0; dt < 4; ++dt) oacc[dt][r] *= a2;
        }
      }

      uint32_t c0 = cvtpk_bf16(st[0],  st[1]),  c1 = cvtpk_bf16(st[2],  st[3]);
      uint32_t c2 = cvtpk_bf16(st[4],  st[5]),  c3 = cvtpk_bf16(st[6],  st[7]);
      uint32_t c4 = cvtpk_bf16(st[8],  st[9]),  c5 = cvtpk_bf16(st[10], st[11]);
      uint32_t c6 = cvtpk_bf16(st[12], st[13]), c7 = cvtpk_bf16(st[14], st[15]);
      { auto rr = __builtin_amdgcn_permlane32_swap(c0, c2, false, false); c0 = rr[0]; c2 = rr[1]; }
      { auto rr = __builtin_amdgcn_permlane32_swap(c1, c3, false, false); c1 = rr[0]; c3 = rr[1]; }
      { auto rr = __builtin_amdgcn_permlane32_swap(c4, c6, false, false); c4 = rr[0]; c6 = rr[1]; }
      { auto rr = __builtin_amdgcn_permlane32_swap(c5, c7, false, false); c5 = rr[0]; c7 = rr[1]; }
      FragU pa, pb;
      pa.w[0] = c0; pa.w[1] = c1; pa.w[2] = c2; pa.w[3] = c3;
      pb.w[0] = c4; pb.w[1] = c5; pb.w[2] = c6; pb.w[3] = c7;

      #pragma unroll
      for (int dt = 0; dt < 4; ++dt) {
        int drow = dt * 32 + lq;
        int pos0 = (ct * 4 + hi) ^ (drow & 7);
        bf16x8 vf0 = *(const bf16x8*)&sVt[drow * 64 + (pos0 << 3)];
        oacc[dt] = MFMA32(pa.v, vf0, oacc[dt]);
        int pos1 = (ct * 4 + 2 + hi) ^ (drow & 7);
        bf16x8 vf1 = *(const bf16x8*)&sVt[drow * 64 + (pos1 << 3)];
        oacc[dt] = MFMA32(pb.v, vf1, oacc[dt]);
      }
    }
  }

  if (hi == 0) sRed[warp * 32 + lq] = l;
  asm volatile("s_waitcnt lgkmcnt(0)" ::: "memory");
  #pragma unroll
  for (int r = 0; r < 16; ++r) {
    int cr = (r & 3) + 8 * (r >> 2) + 4 * hi;
    int qr = q0 + warp * 32 + cr;
    if (qr < Lq) {
      float rn = 1.0f / sRed[warp * 32 + cr];
      float* op = out + ((size_t)(s0q + qr) * H + h) * D + lq;
      #pragma unroll
      for (int dt = 0; dt < 4; ++dt)
        op[dt * 32] = oacc[dt][r] * rn;
    }
  }
}

extern "C" void kernel_launch(void* const* d_in, const int* in_sizes, int n_in,
                              void* d_out, int out_size, void* d_ws, size_t ws_size,
                              hipStream_t stream) {
  const float* q = (const float*)d_in[0];
  const float* k = (const float*)d_in[1];
  const float* v = (const float*)d_in[2];
  const int* cuq = (const int*)d_in[3];
  const int* cuk = (const int*)d_in[4];
  float* out = (float*)d_out;

  int total = in_sizes[0] / (H * D);
  int nseq = in_sizes[3] - 1;
  int maxtiles = (total + BM - 1) / BM + nseq;

  size_t needK = (size_t)in_sizes[1] * 2;
  size_t needV = (size_t)in_sizes[2] * 2;

  dim3 grid(maxtiles, H);

  if (ws_size >= needK + needV) {
    bf16_t* kb = (bf16_t*)d_ws;
    bf16_t* vtb = (bf16_t*)((char*)d_ws + needK);

    conv_k<<<1024, 256, 0, stream>>>(k, kb, in_sizes[1] / 8);
    int maxvt = total / 64 + nseq;
    dim3 gvt(maxvt, H);
    conv_vt<<<gvt, 128, 0, stream>>>(v, vtb, cuk, nseq);
    fa_varlen3<<<grid, NT, 0, stream>>>(q, kb, vtb, cuq, cuk, out, nseq);
  } else {
    fa_varlen2<<<grid, NT, 0, stream>>>(q, k, v, cuq, cuk, out, nseq);
  }
}